// Round 11
// baseline (94.339 us; speedup 1.0000x reference)
//
#include <hip/hip_runtime.h>
#include <math.h>

// Match numpy's unfused f32 arithmetic (fma contraction shifts IoU at the
// 0.45 decision boundary). R1-R10 with this pragma matched absmax 0.0.
#pragma clang fp contract(off)

#define PNUM    3000
#define NCLS    21
#define TOPK    200
#define BLOCK   1024
#define CHUNK   1024
#define BATCH   128
#define NMS_T   0.45f
#define LO_BITS 0x3C23D70Bu          // smallest float bits strictly > 0.01f
#define HI_BITS 0x3F800001u          // > bits of any score in [0,1]
#define MAXKEEP (TOPK + BATCH)       // cnt<=199 entering a round, +<=128 keeps

// Refill ladder: rung 0 = [0.70, 1.0), then 0.05-wide rungs down to 0.05,
// final rung ends at LO_BITS. Boundaries only affect performance, not
// correctness (each rung is fully sorted; rungs descend by score).
__device__ __constant__ unsigned LADDER[15] = {
    0x3F333333u, 0x3F266666u, 0x3F19999Au, 0x3F0CCCCDu, 0x3F000000u,
    0x3EE66666u, 0x3ECCCCCDu, 0x3EB33333u, 0x3E99999Au, 0x3E800000u,
    0x3E4CCCCDu, 0x3E19999Au, 0x3DCCCCCDu, 0x3D4CCCCDu, LO_BITS };

__device__ __forceinline__ float iou_f(float4 a, float aa, float4 b, float ab) {
    float ltx = fmaxf(a.x, b.x);
    float lty = fmaxf(a.y, b.y);
    float rbx = fminf(a.z, b.z);
    float rby = fminf(a.w, b.w);
    float iw  = fmaxf(rbx - ltx, 0.0f);
    float ih  = fmaxf(rby - lty, 0.0f);
    float inter = iw * ih;
    float uni   = aa + ab - inter;           // keeper area first (ref order)
    return inter / fmaxf(uni, 1e-12f);
}

// One block per (image b, class c). R9/R10 selection/sort/decode + NMS in
// 128-candidate rounds, ONE barrier each. Wave w owns candidate-ROWS
// 8w..8w+7: full 128-bit suppressor mask per row via two ballots (single
// writer per word -> resolve reads 3 words, no 16-way OR). CK dead bits:
// 8 strides/candidate across wave pairs. Resolve replicated in all waves
// (2-word fixpoint = exact greedy recurrence); keep-list writes redundant
// and bit-identical per wave; waves 0/1 emit global rows.
__global__ __launch_bounds__(BLOCK) void ssd_nms_kernel(
    const float* __restrict__ loc,     // [B, PNUM, 4]
    const float* __restrict__ conf,    // [B, PNUM, NCLS]
    const float* __restrict__ priors,  // [PNUM, 4]
    float* __restrict__ out)           // [B, NCLS, TOPK, 5]
{
    const int c   = blockIdx.x;
    const int b   = blockIdx.y;
    const int tid = threadIdx.x;

    float* outbase = out + ((size_t)(b * NCLS + c)) * (TOPK * 5);

    if (c == 0) {
        for (int i = tid; i < TOPK * 5; i += BLOCK) outbase[i] = 0.0f;
        return;
    }

    __shared__ unsigned long long s_bufA[CHUNK];        // 8 KB  sort ping
    __shared__ unsigned long long s_bufB[CHUNK];        // 8 KB  sort pong
    __shared__ float4             s_box[CHUNK];         // 16 KB decoded chunk boxes
    __shared__ float              s_area[CHUNK];        // 4 KB
    __shared__ float              s_score[CHUNK];       // 4 KB
    __shared__ float4             s_kb[MAXKEEP];        // committed keep boxes
    __shared__ float              s_ka[MAXKEEP];
    __shared__ unsigned long long s_supT[2][BATCH][2];  // 4 KB row masks (parity)
    __shared__ unsigned long long s_deadT[2][16];       // per-wave dead ballots
    __shared__ int                s_wcnt[16];           // per-wave counts (fallback)
    __shared__ int s_m;

    const int lane = tid & 63;
    const int wav  = tid >> 6;

    // ---- per-thread score bits in registers (elements tid + q*1024) ----
    unsigned hb[4];
    const float* confb = conf + ((size_t)b * PNUM) * NCLS + c;
    #pragma unroll
    for (int q = 0; q < 4; ++q) {
        int i = tid + (q << 10);
        unsigned h = 0u;
        if (i < PNUM) {
            float s = confb[(size_t)i * NCLS];
            if (s > 0.01f) h = __float_as_uint(s);
        }
        hb[q] = h;
    }

    unsigned Thi = HI_BITS;
    int rung = 0;
    int cnt = 0;                 // committed keeps: register, uniform across waves
    bool done = false;

    for (;;) {   // ================= chunk loop =================
        unsigned T = LADDER[rung];

        // ---- optimistic compact of [T, Thi) (no count pass) ----
        __syncthreads();                 // protect s_bufA / s_m reuse
        if (tid == 0) s_m = 0;
        s_bufA[tid] = 0ull;              // pad keys sort last (desc)
        __syncthreads();
        #pragma unroll
        for (int q = 0; q < 4; ++q) {
            unsigned sb = hb[q];
            bool p = (sb >= T && sb < Thi);
            unsigned long long bal = __ballot(p);
            int wb = 0;
            if (lane == 0 && bal) wb = atomicAdd(&s_m, (int)__popcll(bal));
            wb = __shfl(wb, 0);
            if (p) {
                int dst = wb + (int)__popcll(bal & ((1ull << lane) - 1ull));
                if (dst < CHUNK) {
                    int i = tid + (q << 10);
                    s_bufA[dst] = ((unsigned long long)sb << 32) | (unsigned)(~i);
                }
            }
        }
        __syncthreads();
        int M = s_m;

        if (M > CHUNK) {
            // ---- rare fallback: bisect smallest T' in (T, Thi] with count
            //      <= CHUNK, then deterministic count+compact ----
            unsigned lo = T + 1, hi = Thi;
            while (lo < hi) {
                unsigned mid = lo + ((hi - lo) >> 1);
                __syncthreads();
                int c2 = 0;
                #pragma unroll
                for (int q = 0; q < 4; ++q)
                    c2 += (int)__popcll(__ballot(hb[q] >= mid && hb[q] < Thi));
                if (lane == 0) s_wcnt[wav] = c2;
                __syncthreads();
                int n = 0;
                #pragma unroll
                for (int w = 0; w < 16; ++w) n += s_wcnt[w];
                if (n <= CHUNK) hi = mid; else lo = mid + 1;
            }
            T = hi;
            // deterministic count + compact with final T
            __syncthreads();
            int wc = 0;
            #pragma unroll
            for (int q = 0; q < 4; ++q)
                wc += (int)__popcll(__ballot(hb[q] >= T && hb[q] < Thi));
            if (lane == 0) s_wcnt[wav] = wc;
            s_bufA[tid] = 0ull;
            __syncthreads();
            int wbase = 0; M = 0;
            #pragma unroll
            for (int w = 0; w < 16; ++w) {
                int v = s_wcnt[w];
                M += v;
                if (w < wav) wbase += v;
            }
            int base = wbase;
            #pragma unroll
            for (int q = 0; q < 4; ++q) {
                unsigned sb = hb[q];
                bool p = (sb >= T && sb < Thi);
                unsigned long long bal = __ballot(p);
                if (p) {
                    int dst = base + (int)__popcll(bal & ((1ull << lane) - 1ull));
                    int i = tid + (q << 10);
                    s_bufA[dst] = ((unsigned long long)sb << 32) | (unsigned)(~i);
                }
                base += (int)__popcll(bal);
            }
            __syncthreads();
        }

        if (M == 0) {
            if (T <= LO_BITS) break;       // nothing left at all
            Thi = T;
            while (rung < 14 && LADDER[rung] >= T) rung++;
            continue;
        }

        // ---- width-adaptive register bitonic sort, descending ----
        unsigned N = 64;
        while (N < (unsigned)M) N <<= 1;
        unsigned long long key = s_bufA[tid];
        int parity = 0;
        for (unsigned k = 2; k <= N; k <<= 1) {
            for (unsigned j = k >> 1; j > 0; j >>= 1) {
                unsigned long long pk;
                if (j >= 64) {
                    unsigned long long* buf = parity ? s_bufB : s_bufA;
                    buf[tid] = key;
                    __syncthreads();
                    pk = buf[tid ^ j];
                    parity ^= 1;
                } else {
                    pk = __shfl_xor(key, (int)j, 64);
                }
                bool takeMax  = (((tid & j) == 0) == ((tid & k) == 0));
                bool pGreater = pk > key;
                if (takeMax == pGreater) key = pk;
            }
        }

        // ---- decode chunk boxes (thread tid == sorted rank tid) ----
        if (key != 0ull) {
            unsigned idx = ~(unsigned)key;        // original prior index
            float4 l  = ((const float4*)loc)[(size_t)b * PNUM + idx];
            float4 pr = ((const float4*)priors)[idx];
            float cx = pr.x + l.x * 0.1f * pr.z;
            float cy = pr.y + l.y * 0.1f * pr.w;
            float w  = pr.z * expf(l.z * 0.2f);
            float h  = pr.w * expf(l.w * 0.2f);
            float x1 = cx - 0.5f * w;
            float y1 = cy - 0.5f * h;
            float x2 = x1 + w;
            float y2 = y1 + h;
            s_box[tid]   = make_float4(x1, y1, x2, y2);
            s_area[tid]  = (x2 - x1) * (y2 - y1);
            s_score[tid] = __uint_as_float((unsigned)(key >> 32));
        }
        __syncthreads();

        // ---- greedy rounds: 128 sorted positions, ONE barrier per round ----
        int pos = 0;
        int parityR = 0;
        while (pos < M) {
            int bn = M - pos; if (bn > BATCH) bn = BATCH;

            // phase 1a: CK dead bits. cid = ((wav&1)<<6)|lane, 8 strides.
            {
                int cid = ((wav & 1) << 6) | lane;
                bool bad = false;
                if (cid < bn) {
                    float4 bC = s_box[pos + cid];
                    float  aC = s_area[pos + cid];
                    #pragma unroll 2
                    for (int K = (wav >> 1); K < cnt; K += 8)
                        bad |= (iou_f(s_kb[K], s_ka[K], bC, aC) > NMS_T);
                }
                unsigned long long db = __ballot(bad);
                if (lane == 0) s_deadT[parityR][wav] = db;
            }
            // phase 1b: triangle rows 8*wav .. 8*wav+7 (single writer/row)
            {
                int i0 = pos + lane;        if (i0 >= M) i0 = pos;
                int i1 = pos + 64 + lane;   if (i1 >= M) i1 = pos;
                float4 bC0 = s_box[i0]; float aC0 = s_area[i0];
                float4 bC1 = s_box[i1]; float aC1 = s_area[i1];
                #pragma unroll
                for (int rr = 0; rr < 8; ++rr) {
                    int row = (wav << 3) | rr;
                    if (row >= bn) break;              // uniform per wave
                    float4 bR = s_box[pos + row];      // broadcast
                    float  aR = s_area[pos + row];
                    // preds auto-masked: col < row < bn
                    bool p0 = (lane < row) &&
                              (iou_f(bC0, aC0, bR, aR) > NMS_T);
                    bool p1 = (64 + lane < row) &&
                              (iou_f(bC1, aC1, bR, aR) > NMS_T);
                    unsigned long long b0 = __ballot(p0);
                    unsigned long long b1 = __ballot(p1);
                    if (lane == 0) {
                        s_supT[parityR][row][0] = b0;
                        s_supT[parityR][row][1] = b1;
                    }
                }
            }
            __syncthreads();

            // phase 2: replicated 2-word fixpoint resolve (identical per wave)
            unsigned long long dead0 = 0ull, dead1 = 0ull;
            #pragma unroll
            for (int w = 0; w < 16; w += 2) {
                dead0 |= s_deadT[parityR][w];
                dead1 |= s_deadT[parityR][w + 1];
            }
            unsigned long long own0 = s_supT[parityR][lane][0];
            unsigned long long o1lo = s_supT[parityR][64 + lane][0];
            unsigned long long o1hi = s_supT[parityR][64 + lane][1];

            int bn0 = bn < 64 ? bn : 64;
            int bn1 = bn > 64 ? bn - 64 : 0;
            unsigned long long am0 =
                ((bn0 == 64) ? ~0ull : ((1ull << bn0) - 1ull)) & ~dead0;
            unsigned long long am1 =
                ((bn1 == 64) ? ~0ull : ((1ull << bn1) - 1ull)) & ~dead1;
            bool alive0 = (am0 >> lane) & 1ull;
            bool alive1 = (am1 >> lane) & 1ull;
            unsigned long long kept0 = __ballot(alive0 && own0 == 0ull);
            unsigned long long kept1 = __ballot(alive1 && o1lo == 0ull && o1hi == 0ull);
            unsigned long long und0 = am0 & ~kept0;
            unsigned long long und1 = am1 & ~kept1;
            while (und0 | und1) {
                // lowest undecided candidate always decides (its suppressors,
                // all lower-indexed, are already decided) -> guaranteed progress
                bool iU0 = (und0 >> lane) & 1ull;
                bool iU1 = (und1 >> lane) & 1ull;
                bool d0 = iU0 && (own0 & kept0) != 0ull;
                bool k0 = iU0 && (own0 & kept0) == 0ull && (own0 & und0) == 0ull;
                unsigned long long hit1 = (o1lo & kept0) | (o1hi & kept1);
                unsigned long long pen1 = (o1lo & und0)  | (o1hi & und1);
                bool d1 = iU1 && hit1 != 0ull;
                bool k1 = iU1 && hit1 == 0ull && pen1 == 0ull;
                unsigned long long nk0 = __ballot(k0), nd0 = __ballot(d0);
                unsigned long long nk1 = __ballot(k1), nd1 = __ballot(d1);
                kept0 |= nk0; und0 &= ~(nk0 | nd0);
                kept1 |= nk1; und1 &= ~(nk1 | nd1);
            }

            int n0 = (int)__popcll(kept0), n1 = (int)__popcll(kept1);
            if ((kept0 >> lane) & 1ull) {
                int krank = (int)__popcll(kept0 & ((1ull << lane) - 1ull));
                int kid = cnt + krank;               // < MAXKEEP
                int sl  = pos + lane;
                float4 bx = s_box[sl];
                s_kb[kid] = bx;                      // redundant identical writes
                s_ka[kid] = s_area[sl];              // (one per wave): benign race
                if (wav == 0 && kid < TOPK) {
                    float* o = outbase + (size_t)kid * 5;
                    o[0] = s_score[sl];
                    o[1] = bx.x; o[2] = bx.y; o[3] = bx.z; o[4] = bx.w;
                }
            }
            if ((kept1 >> lane) & 1ull) {
                int krank = n0 + (int)__popcll(kept1 & ((1ull << lane) - 1ull));
                int kid = cnt + krank;               // < MAXKEEP
                int sl  = pos + 64 + lane;
                float4 bx = s_box[sl];
                s_kb[kid] = bx;
                s_ka[kid] = s_area[sl];
                if (wav == 1 && kid < TOPK) {
                    float* o = outbase + (size_t)kid * 5;
                    o[0] = s_score[sl];
                    o[1] = bx.x; o[2] = bx.y; o[3] = bx.z; o[4] = bx.w;
                }
            }
            cnt += n0 + n1;                          // uniform across waves
            if (cnt >= TOPK) { done = true; break; } // first TOPK rows fixed
            pos += bn;
            parityR ^= 1;
        }

        if (done) break;
        if (T <= LO_BITS) break;                  // all candidates consumed
        Thi = T;                                  // next rung: scores in [?, T)
        while (rung < 14 && LADDER[rung] >= T) rung++;
    }

    // ---- zero unwritten tail rows ----
    __syncthreads();
    const int cf = cnt < TOPK ? cnt : TOPK;
    for (int r = cf + tid; r < TOPK; r += BLOCK) {
        float* o = outbase + (size_t)r * 5;
        o[0] = 0.f; o[1] = 0.f; o[2] = 0.f; o[3] = 0.f; o[4] = 0.f;
    }
}

extern "C" void kernel_launch(void* const* d_in, const int* in_sizes, int n_in,
                              void* d_out, int out_size, void* d_ws, size_t ws_size,
                              hipStream_t stream) {
    const float* loc    = (const float*)d_in[0];
    const float* conf   = (const float*)d_in[1];
    const float* priors = (const float*)d_in[2];
    float* out          = (float*)d_out;
    const int B = in_sizes[0] / (PNUM * 4);   // 8
    dim3 grid(NCLS, B);
    ssd_nms_kernel<<<grid, BLOCK, 0, stream>>>(loc, conf, priors, out);
}

// Round 12
// 91.394 us; speedup vs baseline: 1.0322x; 1.0322x over previous
//
#include <hip/hip_runtime.h>
#include <math.h>

// Match numpy's unfused f32 arithmetic (fma contraction shifts IoU at the
// 0.45 decision boundary). R1-R11 with this pragma matched absmax 0.0.
#pragma clang fp contract(off)

#define PNUM    3000
#define NCLS    21
#define TOPK    200
#define BLOCK   1024
#define CHUNK   1024
#define NMS_T   0.45f
#define LO_BITS 0x3C23D70Bu          // smallest float bits strictly > 0.01f
#define HI_BITS 0x3F800001u          // > bits of any score in [0,1]
#define MAXKEEP (TOPK + 64)

// Refill ladder: rung 0 = [0.70, 1.0), then 0.05-wide rungs down to 0.05,
// final rung ends at LO_BITS. Boundaries only affect performance, not
// correctness (each rung is fully sorted; rungs descend by score).
__device__ __constant__ unsigned LADDER[15] = {
    0x3F333333u, 0x3F266666u, 0x3F19999Au, 0x3F0CCCCDu, 0x3F000000u,
    0x3EE66666u, 0x3ECCCCCDu, 0x3EB33333u, 0x3E99999Au, 0x3E800000u,
    0x3E4CCCCDu, 0x3E19999Au, 0x3DCCCCCDu, 0x3D4CCCCDu, LO_BITS };

__device__ __forceinline__ float iou_f(float4 a, float aa, float4 b, float ab) {
    float ltx = fmaxf(a.x, b.x);
    float lty = fmaxf(a.y, b.y);
    float rbx = fminf(a.z, b.z);
    float rby = fminf(a.w, b.w);
    float iw  = fmaxf(rbx - ltx, 0.0f);
    float ih  = fmaxf(rby - lty, 0.0f);
    float inter = iw * ih;
    float uni   = aa + ab - inter;           // keeper area first (ref order)
    return inter / fmaxf(uni, 1e-12f);
}

// LOCKED-IN BEST (R9, harness 91.7 us / kernel ~38 us): one block per
// (image b, class c). Fixed threshold-ladder selection with optimistic
// ballot compaction (bisect fallback for exactness), width-adaptive register
// bitonic sort (shfl j<64, ping-pong LDS j>=64), decode, then lazy greedy
// NMS in 64-candidate rounds: branchless committed-keep check across 16
// waves + per-lane in-batch suppressor words; wave0 resolves the exact
// greedy recurrence sparsely (immediate-keep ballot + serial loop only over
// suppressor-holding lanes). R10 (1-barrier replicated resolve) and R11
// (128-batch row-sliced triangle) both measured neutral-to-worse; the round
// machinery is balanced (barriers ~ resolve ~ IoU work), so this structure
// is the practical serialization floor for the task.
__global__ __launch_bounds__(BLOCK) void ssd_nms_kernel(
    const float* __restrict__ loc,     // [B, PNUM, 4]
    const float* __restrict__ conf,    // [B, PNUM, NCLS]
    const float* __restrict__ priors,  // [PNUM, 4]
    float* __restrict__ out)           // [B, NCLS, TOPK, 5]
{
    const int c   = blockIdx.x;
    const int b   = blockIdx.y;
    const int tid = threadIdx.x;

    float* outbase = out + ((size_t)(b * NCLS + c)) * (TOPK * 5);

    if (c == 0) {
        for (int i = tid; i < TOPK * 5; i += BLOCK) outbase[i] = 0.0f;
        return;
    }

    __shared__ unsigned long long s_bufA[CHUNK];  // 8 KB  sort ping
    __shared__ unsigned long long s_bufB[CHUNK];  // 8 KB  sort pong
    __shared__ float4             s_box[CHUNK];   // 16 KB decoded chunk boxes
    __shared__ float              s_area[CHUNK];  // 4 KB
    __shared__ float              s_score[CHUNK]; // 4 KB
    __shared__ float4             s_kb[MAXKEEP];  // committed keep boxes
    __shared__ float              s_ka[MAXKEEP];
    __shared__ unsigned long long s_supp[64];     // in-batch suppression bits
    __shared__ int                s_supc[64];     // suppressed-by-committed flag
    __shared__ int                s_wcnt[16];     // per-wave counts (fallback)
    __shared__ int s_m, s_cnt, s_done;

    const int lane = tid & 63;
    const int wav  = tid >> 6;

    // ---- per-thread score bits in registers (elements tid + q*1024) ----
    unsigned hb[4];
    const float* confb = conf + ((size_t)b * PNUM) * NCLS + c;
    #pragma unroll
    for (int q = 0; q < 4; ++q) {
        int i = tid + (q << 10);
        unsigned h = 0u;
        if (i < PNUM) {
            float s = confb[(size_t)i * NCLS];
            if (s > 0.01f) h = __float_as_uint(s);
        }
        hb[q] = h;
    }
    if (tid < 64) { s_supp[lane] = 0ull; s_supc[lane] = 0; }
    if (tid == 0) { s_cnt = 0; s_done = 0; }
    // (published by the first barrier below)

    unsigned Thi = HI_BITS;
    int rung = 0;
    bool done = false;

    for (;;) {   // ================= chunk loop =================
        unsigned T = LADDER[rung];

        // ---- optimistic compact of [T, Thi) (no count pass) ----
        __syncthreads();                 // protect s_bufA / s_m reuse
        if (tid == 0) s_m = 0;
        s_bufA[tid] = 0ull;              // pad keys sort last (desc)
        __syncthreads();
        #pragma unroll
        for (int q = 0; q < 4; ++q) {
            unsigned sb = hb[q];
            bool p = (sb >= T && sb < Thi);
            unsigned long long bal = __ballot(p);
            int wb = 0;
            if (lane == 0 && bal) wb = atomicAdd(&s_m, (int)__popcll(bal));
            wb = __shfl(wb, 0);
            if (p) {
                int dst = wb + (int)__popcll(bal & ((1ull << lane) - 1ull));
                if (dst < CHUNK) {
                    int i = tid + (q << 10);
                    s_bufA[dst] = ((unsigned long long)sb << 32) | (unsigned)(~i);
                }
            }
        }
        __syncthreads();
        int M = s_m;

        if (M > CHUNK) {
            // ---- rare fallback: bisect smallest T' in (T, Thi] with count
            //      <= CHUNK, then deterministic count+compact ----
            unsigned lo = T + 1, hi = Thi;
            while (lo < hi) {
                unsigned mid = lo + ((hi - lo) >> 1);
                __syncthreads();
                int c2 = 0;
                #pragma unroll
                for (int q = 0; q < 4; ++q)
                    c2 += (int)__popcll(__ballot(hb[q] >= mid && hb[q] < Thi));
                if (lane == 0) s_wcnt[wav] = c2;
                __syncthreads();
                int n = 0;
                #pragma unroll
                for (int w = 0; w < 16; ++w) n += s_wcnt[w];
                if (n <= CHUNK) hi = mid; else lo = mid + 1;
            }
            T = hi;
            // deterministic count + compact with final T
            __syncthreads();
            int wc = 0;
            #pragma unroll
            for (int q = 0; q < 4; ++q)
                wc += (int)__popcll(__ballot(hb[q] >= T && hb[q] < Thi));
            if (lane == 0) s_wcnt[wav] = wc;
            s_bufA[tid] = 0ull;
            __syncthreads();
            int wbase = 0; M = 0;
            #pragma unroll
            for (int w = 0; w < 16; ++w) {
                int v = s_wcnt[w];
                M += v;
                if (w < wav) wbase += v;
            }
            int base = wbase;
            #pragma unroll
            for (int q = 0; q < 4; ++q) {
                unsigned sb = hb[q];
                bool p = (sb >= T && sb < Thi);
                unsigned long long bal = __ballot(p);
                if (p) {
                    int dst = base + (int)__popcll(bal & ((1ull << lane) - 1ull));
                    int i = tid + (q << 10);
                    s_bufA[dst] = ((unsigned long long)sb << 32) | (unsigned)(~i);
                }
                base += (int)__popcll(bal);
            }
            __syncthreads();
        }

        if (M == 0) {
            if (T <= LO_BITS) break;       // nothing left at all
            Thi = T;
            while (rung < 14 && LADDER[rung] >= T) rung++;
            continue;
        }

        // ---- width-adaptive register bitonic sort, descending ----
        // N = next pow2 >= M (>=64). Lanes >= N hold zero keys: harmless in
        // shfl stages (zeros swap with zeros) and LDS stages (read/write the
        // unused upper region). Barriers are uniform (N is block-uniform).
        unsigned N = 64;
        while (N < (unsigned)M) N <<= 1;
        unsigned long long key = s_bufA[tid];
        int parity = 0;
        for (unsigned k = 2; k <= N; k <<= 1) {
            for (unsigned j = k >> 1; j > 0; j >>= 1) {
                unsigned long long pk;
                if (j >= 64) {
                    unsigned long long* buf = parity ? s_bufB : s_bufA;
                    buf[tid] = key;
                    __syncthreads();
                    pk = buf[tid ^ j];
                    parity ^= 1;
                } else {
                    pk = __shfl_xor(key, (int)j, 64);
                }
                bool takeMax  = (((tid & j) == 0) == ((tid & k) == 0));
                bool pGreater = pk > key;
                if (takeMax == pGreater) key = pk;
            }
        }

        // ---- decode chunk boxes (thread tid == sorted rank tid) ----
        if (key != 0ull) {
            unsigned idx = ~(unsigned)key;        // original prior index
            float4 l  = ((const float4*)loc)[(size_t)b * PNUM + idx];
            float4 pr = ((const float4*)priors)[idx];
            float cx = pr.x + l.x * 0.1f * pr.z;
            float cy = pr.y + l.y * 0.1f * pr.w;
            float w  = pr.z * expf(l.z * 0.2f);
            float h  = pr.w * expf(l.w * 0.2f);
            float x1 = cx - 0.5f * w;
            float y1 = cy - 0.5f * h;
            float x2 = x1 + w;
            float y2 = y1 + h;
            s_box[tid]   = make_float4(x1, y1, x2, y2);
            s_area[tid]  = (x2 - x1) * (y2 - y1);
            s_score[tid] = __uint_as_float((unsigned)(key >> 32));
        }
        __syncthreads();

        // ---- lazy greedy rounds: 64 sorted positions per round ----
        int pos = 0;
        while (pos < M) {
            int bn  = M - pos; if (bn > 64) bn = 64;
            int cnt = s_cnt;                      // published at last barrier

            // CK: all 16 waves check candidates vs committed keeps + in-batch.
            // Branchless over keeps: lets the LDS loads pipeline (no early exit).
            if (lane < bn) {
                float4 bL = s_box[pos + lane];
                float  aL = s_area[pos + lane];
                bool bad = false;
                #pragma unroll 2
                for (int K = wav; K < cnt; K += 16)
                    bad |= (iou_f(s_kb[K], s_ka[K], bL, aL) > NMS_T);
                if (bad) s_supc[lane] = 1;        // all writers store 1: race-safe
                unsigned long long bits = 0ull;
                int M0 = wav << 2;
                #pragma unroll
                for (int q2 = 0; q2 < 4; ++q2) {
                    int Mi = M0 + q2;
                    if (Mi < lane) {
                        if (iou_f(s_box[pos + Mi], s_area[pos + Mi], bL, aL) > NMS_T)
                            bits |= (1ull << Mi);
                    }
                }
                if (bits) atomicOr(&s_supp[lane], bits);
            }
            __syncthreads();

            // D: wave0 resolves greedy recurrence SPARSELY, emits keeps
            if (tid < 64) {
                unsigned long long own      = s_supp[lane];
                unsigned long long deadmask = __ballot(s_supc[lane] != 0);
                bool alive = (lane < bn) && !((deadmask >> lane) & 1ull);
                unsigned long long kept = __ballot(alive && own == 0ull);
                unsigned long long todo = __ballot(alive && own != 0ull);
                while (todo) {
                    int L = __ffsll(todo) - 1;
                    unsigned long long ownL = __shfl(own, L, 64);
                    if (!(ownL & kept)) kept |= 1ull << L;
                    todo &= todo - 1;
                }
                int keptN = (int)__popcll(kept);
                bool me   = (kept >> lane) & 1ull;
                int krank = (int)__popcll(kept & ((1ull << lane) - 1ull));
                if (me) {
                    int kid = cnt + krank;        // < MAXKEEP by construction
                    float4 bx = s_box[pos + lane];
                    s_kb[kid] = bx;
                    s_ka[kid] = s_area[pos + lane];
                    if (kid < TOPK) {
                        float* o = outbase + (size_t)kid * 5;
                        o[0] = s_score[pos + lane];
                        o[1] = bx.x; o[2] = bx.y; o[3] = bx.z; o[4] = bx.w;
                    }
                }
                s_supp[lane] = 0ull;              // reset for next round
                s_supc[lane] = 0;
                if (lane == 0) {
                    s_cnt  = cnt + keptN;
                    s_done = (cnt + keptN >= TOPK) ? 1 : 0;
                }
            }
            __syncthreads();
            if (s_done) { done = true; break; }   // first TOPK rows fixed
            pos += bn;
        }

        if (done) break;
        if (T <= LO_BITS) break;                  // all candidates consumed
        Thi = T;                                  // next rung: scores in [?, T)
        // advance rung index past any boundary == T (bisect may have raised T)
        while (rung < 14 && LADDER[rung] >= T) rung++;
    }

    // ---- zero unwritten tail rows ----
    const int cf = s_cnt < TOPK ? s_cnt : TOPK;
    for (int r = cf + tid; r < TOPK; r += BLOCK) {
        float* o = outbase + (size_t)r * 5;
        o[0] = 0.f; o[1] = 0.f; o[2] = 0.f; o[3] = 0.f; o[4] = 0.f;
    }
}

extern "C" void kernel_launch(void* const* d_in, const int* in_sizes, int n_in,
                              void* d_out, int out_size, void* d_ws, size_t ws_size,
                              hipStream_t stream) {
    const float* loc    = (const float*)d_in[0];
    const float* conf   = (const float*)d_in[1];
    const float* priors = (const float*)d_in[2];
    float* out          = (float*)d_out;
    const int B = in_sizes[0] / (PNUM * 4);   // 8
    dim3 grid(NCLS, B);
    ssd_nms_kernel<<<grid, BLOCK, 0, stream>>>(loc, conf, priors, out);
}